// Round 1
// baseline (652.420 us; speedup 1.0000x reference)
//
#include <hip/hip_runtime.h>

#define IN_DIM 128
#define HID    64

// ---------------- degree / normalization ----------------

__global__ void k_deg_init(float* __restrict__ deg, int n) {
    int i = blockIdx.x * blockDim.x + threadIdx.x;
    if (i < n) deg[i] = 1.0f;  // self-loop weight
}

__global__ void k_deg_accum(const int* __restrict__ dst, const float* __restrict__ ew,
                            float* __restrict__ deg, int e) {
    int i = blockIdx.x * blockDim.x + threadIdx.x;
    if (i < e) atomicAdd(&deg[dst[i]], ew[i]);
}

__global__ void k_dinv(float* __restrict__ deg, int n) {
    int i = blockIdx.x * blockDim.x + threadIdx.x;
    if (i < n) {
        float d = deg[i];
        deg[i] = (d > 0.0f) ? rsqrtf(d) : 0.0f;
    }
}

__global__ void k_norm(const int* __restrict__ src, const int* __restrict__ dst,
                       const float* __restrict__ ew, const float* __restrict__ dinv,
                       float* __restrict__ norm, int e) {
    int i = blockIdx.x * blockDim.x + threadIdx.x;
    if (i < e) norm[i] = dinv[src[i]] * ew[i] * dinv[dst[i]];
}

// ---------------- GEMM1: h0 = x @ W1  (N x 128 @ 128 x 64) ----------------

__global__ __launch_bounds__(256) void k_gemm1(const float* __restrict__ x,
                                               const float* __restrict__ W1,
                                               float* __restrict__ h0, int n) {
    __shared__ float sW[IN_DIM][HID];   // 32 KB
    __shared__ float sX[16][IN_DIM];    // 8 KB
    int tid = threadIdx.x;
    for (int i = tid; i < IN_DIM * HID; i += 256)
        sW[i >> 6][i & 63] = W1[i];
    int row0 = blockIdx.x * 16;
    // stage 16 rows of x (float4 vectorized)
    for (int i = tid; i < 16 * (IN_DIM / 4); i += 256) {
        int r = i / (IN_DIM / 4);
        int c = i % (IN_DIM / 4);
        float4 v;
        if (row0 + r < n)
            v = ((const float4*)x)[(size_t)(row0 + r) * (IN_DIM / 4) + c];
        else
            v = make_float4(0.f, 0.f, 0.f, 0.f);
        ((float4*)&sX[r][0])[c] = v;
    }
    __syncthreads();
    int col = tid & 63;
    int rq  = tid >> 6;
    for (int rr = rq; rr < 16; rr += 4) {
        float acc = 0.0f;
        #pragma unroll 8
        for (int k = 0; k < IN_DIM; ++k)
            acc += sX[rr][k] * sW[k][col];
        int row = row0 + rr;
        if (row < n) h0[(size_t)row * HID + col] = acc;
    }
}

// ---------------- GEMM2: h2pre = relu(h1 + b1) @ W2  (N x 64 @ 64 x 64) ----------------

__global__ __launch_bounds__(256) void k_gemm2(const float* __restrict__ h1,
                                               const float* __restrict__ b1,
                                               const float* __restrict__ W2,
                                               float* __restrict__ h2pre, int n) {
    __shared__ float sW[HID][HID];   // 16 KB
    __shared__ float sX[32][HID];    // 8 KB
    int tid = threadIdx.x;
    for (int i = tid; i < HID * HID; i += 256)
        sW[i >> 6][i & 63] = W2[i];
    int row0 = blockIdx.x * 32;
    for (int i = tid; i < 32 * HID; i += 256) {
        int r = i >> 6, c = i & 63;
        float v = 0.0f;
        if (row0 + r < n) v = h1[(size_t)(row0 + r) * HID + c];
        sX[r][c] = fmaxf(v + b1[c], 0.0f);
    }
    __syncthreads();
    int col = tid & 63;
    int rq  = tid >> 6;
    for (int rr = rq; rr < 32; rr += 4) {
        float acc = 0.0f;
        #pragma unroll 8
        for (int k = 0; k < HID; ++k)
            acc += sX[rr][k] * sW[k][col];
        int row = row0 + rr;
        if (row < n) h2pre[(size_t)row * HID + col] = acc;
    }
}

// ---------------- propagate ----------------

// self-loop contribution; doubles as the initializer of hout (no memset needed)
__global__ void k_prop_self(const float* __restrict__ hin, const float* __restrict__ dinv,
                            float* __restrict__ hout, int n) {
    int idx = blockIdx.x * blockDim.x + threadIdx.x;   // over n*HID
    int i = idx >> 6;
    if (i < n) {
        float di = dinv[i];
        hout[idx] = hin[idx] * di * di;
    }
}

// one wave (64 lanes) per edge; lane = hidden dim
__global__ __launch_bounds__(256) void k_prop_edges(const int* __restrict__ src,
                                                    const int* __restrict__ dst,
                                                    const float* __restrict__ norm,
                                                    const float* __restrict__ hin,
                                                    float* __restrict__ hout, int e) {
    int gid  = blockIdx.x * blockDim.x + threadIdx.x;
    int wid  = gid >> 6;
    int lane = threadIdx.x & 63;
    if (wid >= e) return;
    int   s   = src[wid];
    int   d   = dst[wid];
    float nrm = norm[wid];
    float v = hin[(size_t)s * HID + lane] * nrm;
    atomicAdd(&hout[(size_t)d * HID + lane], v);
}

// ---------------- final: out = relu(h2 + b2) @ Wl + bl ----------------

__global__ __launch_bounds__(256) void k_final(const float* __restrict__ h2,
                                               const float* __restrict__ b2,
                                               const float* __restrict__ Wl,
                                               const float* __restrict__ bl,
                                               float* __restrict__ out, int n) {
    int gid  = blockIdx.x * blockDim.x + threadIdx.x;
    int row  = gid >> 6;
    int lane = threadIdx.x & 63;
    if (row >= n) return;
    float v = fmaxf(h2[(size_t)row * HID + lane] + b2[lane], 0.0f) * Wl[lane];
    for (int off = 32; off > 0; off >>= 1)
        v += __shfl_down(v, off);
    if (lane == 0) out[row] = v + bl[0];
}

// ---------------- launch ----------------

extern "C" void kernel_launch(void* const* d_in, const int* in_sizes, int n_in,
                              void* d_out, int out_size, void* d_ws, size_t ws_size,
                              hipStream_t stream) {
    const float* x   = (const float*)d_in[0];
    const int*   ei  = (const int*)d_in[1];
    const float* ew  = (const float*)d_in[2];
    const float* W1  = (const float*)d_in[3];
    const float* b1  = (const float*)d_in[4];
    const float* W2  = (const float*)d_in[5];
    const float* b2  = (const float*)d_in[6];
    const float* Wl  = (const float*)d_in[7];
    const float* bl  = (const float*)d_in[8];

    const int n = in_sizes[0] / IN_DIM;   // 100000
    const int e = in_sizes[2];            // 1000000
    const int* src = ei;
    const int* dst = ei + e;

    // workspace layout (floats)
    float* ws   = (float*)d_ws;
    float* dinv = ws;                      // n
    float* norm = dinv + n;                // e
    float* A    = norm + e;                // n * HID
    float* B    = A + (size_t)n * HID;     // n * HID

    float* out = (float*)d_out;

    const int B256 = 256;

    // degree + norm
    k_deg_init <<<(n + B256 - 1) / B256, B256, 0, stream>>>(dinv, n);
    k_deg_accum<<<(e + B256 - 1) / B256, B256, 0, stream>>>(dst, ew, dinv, e);
    k_dinv     <<<(n + B256 - 1) / B256, B256, 0, stream>>>(dinv, n);
    k_norm     <<<(e + B256 - 1) / B256, B256, 0, stream>>>(src, dst, ew, dinv, norm, e);

    // layer 1
    k_gemm1<<<(n + 15) / 16, B256, 0, stream>>>(x, W1, A, n);
    k_prop_self <<<((size_t)n * HID + B256 - 1) / B256, B256, 0, stream>>>(A, dinv, B, n);
    k_prop_edges<<<(e + 3) / 4, B256, 0, stream>>>(src, dst, norm, A, B, e);

    // layer 2 (bias1+relu fused into gemm2 load)
    k_gemm2<<<(n + 31) / 32, B256, 0, stream>>>(B, b1, W2, A, n);
    k_prop_self <<<((size_t)n * HID + B256 - 1) / B256, B256, 0, stream>>>(A, dinv, B, n);
    k_prop_edges<<<(e + 3) / 4, B256, 0, stream>>>(src, dst, norm, A, B, e);

    // final linear (bias2+relu fused)
    k_final<<<(n + 3) / 4, B256, 0, stream>>>(B, b2, Wl, bl, out, n);
}

// Round 2
// 433.700 us; speedup vs baseline: 1.5043x; 1.5043x over previous
//
#include <hip/hip_runtime.h>

#define IN_DIM 128
#define HID    64
#define SCAN_B 256

// ---------------- degree / normalization ----------------

__global__ void k_deg_init(float* __restrict__ deg, int n) {
    int i = blockIdx.x * blockDim.x + threadIdx.x;
    if (i < n) deg[i] = 1.0f;  // self-loop weight
}

__global__ void k_deg_accum(const int* __restrict__ dst, const float* __restrict__ ew,
                            float* __restrict__ deg, int e) {
    int i = blockIdx.x * blockDim.x + threadIdx.x;
    if (i < e) atomicAdd(&deg[dst[i]], ew[i]);
}

__global__ void k_dinv(float* __restrict__ deg, int n) {
    int i = blockIdx.x * blockDim.x + threadIdx.x;
    if (i < n) {
        float d = deg[i];
        deg[i] = (d > 0.0f) ? rsqrtf(d) : 0.0f;
    }
}

__global__ void k_norm(const int* __restrict__ src, const int* __restrict__ dst,
                       const float* __restrict__ ew, const float* __restrict__ dinv,
                       float* __restrict__ norm, int e) {
    int i = blockIdx.x * blockDim.x + threadIdx.x;
    if (i < e) norm[i] = dinv[src[i]] * ew[i] * dinv[dst[i]];
}

// ---------------- CSR build: histogram -> scan -> scatter ----------------

__global__ void k_hist(const int* __restrict__ dst, int* __restrict__ counts, int e) {
    int i = blockIdx.x * blockDim.x + threadIdx.x;
    if (i < e) atomicAdd(&counts[dst[i]], 1);
}

// per-block exclusive scan (in-place safe), emit block sums
__global__ __launch_bounds__(SCAN_B) void k_scan1(int* __restrict__ data,
                                                  int* __restrict__ blockSums, int n) {
    __shared__ int s[SCAN_B];
    int tid = threadIdx.x;
    int gid = blockIdx.x * SCAN_B + tid;
    int v = (gid < n) ? data[gid] : 0;
    s[tid] = v;
    __syncthreads();
    for (int off = 1; off < SCAN_B; off <<= 1) {
        int t = (tid >= off) ? s[tid - off] : 0;
        __syncthreads();
        s[tid] += t;
        __syncthreads();
    }
    if (gid < n) data[gid] = s[tid] - v;          // exclusive within block
    if (tid == SCAN_B - 1) blockSums[blockIdx.x] = s[tid];
}

// single-block exclusive scan of block sums (nb <= 512)
__global__ __launch_bounds__(512) void k_scan2(int* __restrict__ blockSums, int nb) {
    __shared__ int s[512];
    int tid = threadIdx.x;
    int v = (tid < nb) ? blockSums[tid] : 0;
    s[tid] = v;
    __syncthreads();
    for (int off = 1; off < 512; off <<= 1) {
        int t = (tid >= off) ? s[tid - off] : 0;
        __syncthreads();
        s[tid] += t;
        __syncthreads();
    }
    if (tid < nb) blockSums[tid] = s[tid] - v;    // exclusive
}

__global__ __launch_bounds__(SCAN_B) void k_scan3(int* __restrict__ data,
                                                  const int* __restrict__ blockSums, int n) {
    int gid = blockIdx.x * SCAN_B + threadIdx.x;
    if (gid < n) data[gid] += blockSums[blockIdx.x];
}

// scatter edges into dst-sorted order; offsets[v] becomes row END afterwards
__global__ void k_scatter(const int* __restrict__ src, const int* __restrict__ dst,
                          const float* __restrict__ ew, const float* __restrict__ dinv,
                          int* __restrict__ offsets, int* __restrict__ ssrc,
                          float* __restrict__ snorm, int e) {
    int i = blockIdx.x * blockDim.x + threadIdx.x;
    if (i >= e) return;
    int s = src[i], d = dst[i];
    int pos = atomicAdd(&offsets[d], 1);
    ssrc[pos]  = s;
    snorm[pos] = dinv[s] * ew[i] * dinv[d];
}

// ---------------- GEMM1: h0 = x @ W1  (N x 128 @ 128 x 64) ----------------

__global__ __launch_bounds__(256) void k_gemm1(const float* __restrict__ x,
                                               const float* __restrict__ W1,
                                               float* __restrict__ h0, int n) {
    __shared__ float sW[IN_DIM][HID];   // 32 KB
    __shared__ float sX[16][IN_DIM];    // 8 KB
    int tid = threadIdx.x;
    for (int i = tid; i < IN_DIM * HID; i += 256)
        sW[i >> 6][i & 63] = W1[i];
    int row0 = blockIdx.x * 16;
    for (int i = tid; i < 16 * (IN_DIM / 4); i += 256) {
        int r = i / (IN_DIM / 4);
        int c = i % (IN_DIM / 4);
        float4 v;
        if (row0 + r < n)
            v = ((const float4*)x)[(size_t)(row0 + r) * (IN_DIM / 4) + c];
        else
            v = make_float4(0.f, 0.f, 0.f, 0.f);
        ((float4*)&sX[r][0])[c] = v;
    }
    __syncthreads();
    int col = tid & 63;
    int rq  = tid >> 6;
    for (int rr = rq; rr < 16; rr += 4) {
        float acc = 0.0f;
        #pragma unroll 8
        for (int k = 0; k < IN_DIM; ++k)
            acc += sX[rr][k] * sW[k][col];
        int row = row0 + rr;
        if (row < n) h0[(size_t)row * HID + col] = acc;
    }
}

// ---------------- GEMM2: h2pre = relu(h1 + b1) @ W2  (N x 64 @ 64 x 64) ----------------

__global__ __launch_bounds__(256) void k_gemm2(const float* __restrict__ h1,
                                               const float* __restrict__ b1,
                                               const float* __restrict__ W2,
                                               float* __restrict__ h2pre, int n) {
    __shared__ float sW[HID][HID];   // 16 KB
    __shared__ float sX[32][HID];    // 8 KB
    int tid = threadIdx.x;
    for (int i = tid; i < HID * HID; i += 256)
        sW[i >> 6][i & 63] = W2[i];
    int row0 = blockIdx.x * 32;
    for (int i = tid; i < 32 * HID; i += 256) {
        int r = i >> 6, c = i & 63;
        float v = 0.0f;
        if (row0 + r < n) v = h1[(size_t)(row0 + r) * HID + c];
        sX[r][c] = fmaxf(v + b1[c], 0.0f);
    }
    __syncthreads();
    int col = tid & 63;
    int rq  = tid >> 6;
    for (int rr = rq; rr < 32; rr += 4) {
        float acc = 0.0f;
        #pragma unroll 8
        for (int k = 0; k < HID; ++k)
            acc += sX[rr][k] * sW[k][col];
        int row = row0 + rr;
        if (row < n) h2pre[(size_t)row * HID + col] = acc;
    }
}

// ---------------- CSR propagate: one wave per dst node, self-loop fused ----------------

__global__ __launch_bounds__(256) void k_prop_csr(const int* __restrict__ rowEnd,
                                                  const int* __restrict__ ssrc,
                                                  const float* __restrict__ snorm,
                                                  const float* __restrict__ hin,
                                                  const float* __restrict__ dinv,
                                                  float* __restrict__ hout, int n) {
    int wid  = (blockIdx.x * blockDim.x + threadIdx.x) >> 6;
    int lane = threadIdx.x & 63;
    if (wid >= n) return;
    int start = (wid == 0) ? 0 : rowEnd[wid - 1];
    int end   = rowEnd[wid];
    float di  = dinv[wid];
    float acc = hin[(size_t)wid * HID + lane] * di * di;   // self-loop, inits acc
    int j = start;
    for (; j + 1 < end; j += 2) {
        int   s0 = ssrc[j],    s1 = ssrc[j + 1];
        float n0 = snorm[j],   n1 = snorm[j + 1];
        float v0 = hin[(size_t)s0 * HID + lane];
        float v1 = hin[(size_t)s1 * HID + lane];
        acc = fmaf(v0, n0, acc);
        acc = fmaf(v1, n1, acc);
    }
    if (j < end) {
        int   s0 = ssrc[j];
        float n0 = snorm[j];
        acc = fmaf(hin[(size_t)s0 * HID + lane], n0, acc);
    }
    hout[(size_t)wid * HID + lane] = acc;
}

// ---------------- fallback atomic propagate (if ws too small for CSR) ----------------

__global__ void k_prop_self(const float* __restrict__ hin, const float* __restrict__ dinv,
                            float* __restrict__ hout, int n) {
    int idx = blockIdx.x * blockDim.x + threadIdx.x;
    int i = idx >> 6;
    if (i < n) {
        float di = dinv[i];
        hout[idx] = hin[idx] * di * di;
    }
}

__global__ __launch_bounds__(256) void k_prop_edges(const int* __restrict__ src,
                                                    const int* __restrict__ dst,
                                                    const float* __restrict__ norm,
                                                    const float* __restrict__ hin,
                                                    float* __restrict__ hout, int e) {
    int gid  = blockIdx.x * blockDim.x + threadIdx.x;
    int wid  = gid >> 6;
    int lane = threadIdx.x & 63;
    if (wid >= e) return;
    int   s   = src[wid];
    int   d   = dst[wid];
    float nrm = norm[wid];
    float v = hin[(size_t)s * HID + lane] * nrm;
    atomicAdd(&hout[(size_t)d * HID + lane], v);
}

// ---------------- final: out = relu(h2 + b2) @ Wl + bl ----------------

__global__ __launch_bounds__(256) void k_final(const float* __restrict__ h2,
                                               const float* __restrict__ b2,
                                               const float* __restrict__ Wl,
                                               const float* __restrict__ bl,
                                               float* __restrict__ out, int n) {
    int gid  = blockIdx.x * blockDim.x + threadIdx.x;
    int row  = gid >> 6;
    int lane = threadIdx.x & 63;
    if (row >= n) return;
    float v = fmaxf(h2[(size_t)row * HID + lane] + b2[lane], 0.0f) * Wl[lane];
    for (int off = 32; off > 0; off >>= 1)
        v += __shfl_down(v, off);
    if (lane == 0) out[row] = v + bl[0];
}

// ---------------- launch ----------------

extern "C" void kernel_launch(void* const* d_in, const int* in_sizes, int n_in,
                              void* d_out, int out_size, void* d_ws, size_t ws_size,
                              hipStream_t stream) {
    const float* x   = (const float*)d_in[0];
    const int*   ei  = (const int*)d_in[1];
    const float* ew  = (const float*)d_in[2];
    const float* W1  = (const float*)d_in[3];
    const float* b1  = (const float*)d_in[4];
    const float* W2  = (const float*)d_in[5];
    const float* b2  = (const float*)d_in[6];
    const float* Wl  = (const float*)d_in[7];
    const float* bl  = (const float*)d_in[8];

    const int n = in_sizes[0] / IN_DIM;   // 100000
    const int e = in_sizes[2];            // 1000000
    const int* src = ei;
    const int* dst = ei + e;

    float* out = (float*)d_out;
    const int B256 = 256;
    const int nScanBlocks = (n + SCAN_B - 1) / SCAN_B;

    // CSR-path workspace layout (4-byte units)
    // [dinv n][offsets n][blockSums 512][ssrc e][snorm e][A n*HID][B n*HID]
    size_t need = ((size_t)n + n + 512 + e + e + (size_t)n * HID * 2) * 4;

    if (ws_size >= need && nScanBlocks <= 512) {
        float* dinv    = (float*)d_ws;
        int*   offsets = (int*)(dinv + n);
        int*   bsums   = offsets + n;
        int*   ssrc    = bsums + 512;
        float* snorm   = (float*)(ssrc + e);
        float* A       = snorm + e;
        float* B       = A + (size_t)n * HID;

        // histogram of dst
        hipMemsetAsync(offsets, 0, (size_t)n * 4, stream);
        k_hist<<<(e + B256 - 1) / B256, B256, 0, stream>>>(dst, offsets, e);

        // degree -> dinv
        k_deg_init <<<(n + B256 - 1) / B256, B256, 0, stream>>>(dinv, n);
        k_deg_accum<<<(e + B256 - 1) / B256, B256, 0, stream>>>(dst, ew, dinv, e);
        k_dinv     <<<(n + B256 - 1) / B256, B256, 0, stream>>>(dinv, n);

        // exclusive scan of counts -> offsets
        k_scan1<<<nScanBlocks, SCAN_B, 0, stream>>>(offsets, bsums, n);
        k_scan2<<<1, 512, 0, stream>>>(bsums, nScanBlocks);
        k_scan3<<<nScanBlocks, SCAN_B, 0, stream>>>(offsets, bsums, n);

        // scatter into dst-sorted arrays (offsets -> row ends)
        k_scatter<<<(e + B256 - 1) / B256, B256, 0, stream>>>(src, dst, ew, dinv,
                                                             offsets, ssrc, snorm, e);

        // layer 1
        k_gemm1<<<(n + 15) / 16, B256, 0, stream>>>(x, W1, A, n);
        k_prop_csr<<<(n + 3) / 4, B256, 0, stream>>>(offsets, ssrc, snorm, A, dinv, B, n);

        // layer 2
        k_gemm2<<<(n + 31) / 32, B256, 0, stream>>>(B, b1, W2, A, n);
        k_prop_csr<<<(n + 3) / 4, B256, 0, stream>>>(offsets, ssrc, snorm, A, dinv, B, n);

        // final
        k_final<<<(n + 3) / 4, B256, 0, stream>>>(B, b2, Wl, bl, out, n);
    } else {
        // fallback: round-1 atomic path
        float* ws   = (float*)d_ws;
        float* dinv = ws;
        float* norm = dinv + n;
        float* A    = norm + e;
        float* B    = A + (size_t)n * HID;

        k_deg_init <<<(n + B256 - 1) / B256, B256, 0, stream>>>(dinv, n);
        k_deg_accum<<<(e + B256 - 1) / B256, B256, 0, stream>>>(dst, ew, dinv, e);
        k_dinv     <<<(n + B256 - 1) / B256, B256, 0, stream>>>(dinv, n);
        k_norm     <<<(e + B256 - 1) / B256, B256, 0, stream>>>(src, dst, ew, dinv, norm, e);

        k_gemm1<<<(n + 15) / 16, B256, 0, stream>>>(x, W1, A, n);
        k_prop_self <<<((size_t)n * HID + B256 - 1) / B256, B256, 0, stream>>>(A, dinv, B, n);
        k_prop_edges<<<(e + 3) / 4, B256, 0, stream>>>(src, dst, norm, A, B, e);

        k_gemm2<<<(n + 31) / 32, B256, 0, stream>>>(B, b1, W2, A, n);
        k_prop_self <<<((size_t)n * HID + B256 - 1) / B256, B256, 0, stream>>>(A, dinv, B, n);
        k_prop_edges<<<(e + 3) / 4, B256, 0, stream>>>(src, dst, norm, A, B, e);

        k_final<<<(n + 3) / 4, B256, 0, stream>>>(B, b2, Wl, bl, out, n);
    }
}

// Round 3
// 353.433 us; speedup vs baseline: 1.8460x; 1.2271x over previous
//
#include <hip/hip_runtime.h>

#define IN_DIM 128
#define HID    64
#define SCAN_B 256

typedef __attribute__((ext_vector_type(4))) _Float16 f16x4;
typedef __attribute__((ext_vector_type(8))) _Float16 f16x8;
typedef __attribute__((ext_vector_type(4))) float    f32x4;

// ---------------- weight prep: f32 -> f16, transposed ----------------
// W1T[c][k] = W1[k][c]  (64 x 128),  W2T[c][k] = W2[k][c]  (64 x 64)
__global__ void k_prep_w(const float* __restrict__ W1, const float* __restrict__ W2,
                         _Float16* __restrict__ W1T, _Float16* __restrict__ W2T) {
    int i = blockIdx.x * blockDim.x + threadIdx.x;
    if (i < IN_DIM * HID) { int k = i >> 6, c = i & 63; W1T[c * IN_DIM + k] = (_Float16)W1[i]; }
    if (i < HID * HID)    { int k = i >> 6, c = i & 63; W2T[c * HID + k]    = (_Float16)W2[i]; }
}

// ---------------- degree ----------------

__global__ void k_deg_init(float* __restrict__ deg, int n) {
    int i = blockIdx.x * blockDim.x + threadIdx.x;
    if (i < n) deg[i] = 1.0f;  // self-loop weight
}

__global__ void k_deg_accum(const int* __restrict__ dst, const float* __restrict__ ew,
                            float* __restrict__ deg, int e) {
    int i = blockIdx.x * blockDim.x + threadIdx.x;
    if (i < e) atomicAdd(&deg[dst[i]], ew[i]);
}

__global__ void k_dinv(float* __restrict__ deg, int n) {
    int i = blockIdx.x * blockDim.x + threadIdx.x;
    if (i < n) {
        float d = deg[i];
        deg[i] = (d > 0.0f) ? rsqrtf(d) : 0.0f;
    }
}

// ---------------- CSR build: histogram -> scan -> scatter ----------------

__global__ void k_hist(const int* __restrict__ dst, int* __restrict__ counts, int e) {
    int i = blockIdx.x * blockDim.x + threadIdx.x;
    if (i < e) atomicAdd(&counts[dst[i]], 1);
}

__global__ __launch_bounds__(SCAN_B) void k_scan1(int* __restrict__ data,
                                                  int* __restrict__ blockSums, int n) {
    __shared__ int s[SCAN_B];
    int tid = threadIdx.x;
    int gid = blockIdx.x * SCAN_B + tid;
    int v = (gid < n) ? data[gid] : 0;
    s[tid] = v;
    __syncthreads();
    for (int off = 1; off < SCAN_B; off <<= 1) {
        int t = (tid >= off) ? s[tid - off] : 0;
        __syncthreads();
        s[tid] += t;
        __syncthreads();
    }
    if (gid < n) data[gid] = s[tid] - v;
    if (tid == SCAN_B - 1) blockSums[blockIdx.x] = s[tid];
}

__global__ __launch_bounds__(512) void k_scan2(int* __restrict__ blockSums, int nb) {
    __shared__ int s[512];
    int tid = threadIdx.x;
    int v = (tid < nb) ? blockSums[tid] : 0;
    s[tid] = v;
    __syncthreads();
    for (int off = 1; off < 512; off <<= 1) {
        int t = (tid >= off) ? s[tid - off] : 0;
        __syncthreads();
        s[tid] += t;
        __syncthreads();
    }
    if (tid < nb) blockSums[tid] = s[tid] - v;
}

__global__ __launch_bounds__(SCAN_B) void k_scan3(int* __restrict__ data,
                                                  const int* __restrict__ blockSums, int n) {
    int gid = blockIdx.x * SCAN_B + threadIdx.x;
    if (gid < n) data[gid] += blockSums[blockIdx.x];
}

__global__ void k_scatter(const int* __restrict__ src, const int* __restrict__ dst,
                          const float* __restrict__ ew, const float* __restrict__ dinv,
                          int* __restrict__ offsets, int* __restrict__ ssrc,
                          float* __restrict__ snorm, int e) {
    int i = blockIdx.x * blockDim.x + threadIdx.x;
    if (i >= e) return;
    int s = src[i], d = dst[i];
    int pos = atomicAdd(&offsets[d], 1);
    ssrc[pos]  = s;
    snorm[pos] = dinv[s] * ew[i] * dinv[d];
}

// ---------------- GEMM1 (MFMA f16): h0 = x @ W1, out f16 ----------------
// block = 256 = 4 waves; each wave owns 16 rows; 4 col-tiles of 16; K=128 in 4 steps of 32.

__global__ __launch_bounds__(256) void k_gemm1(const float* __restrict__ x,
                                               const _Float16* __restrict__ W1T,
                                               _Float16* __restrict__ h0, int n) {
    __shared__ _Float16 sX[4][16 * IN_DIM];   // 16 KB total, 4 KB per wave
    int tid  = threadIdx.x;
    int wave = tid >> 6, lane = tid & 63;
    int row0 = blockIdx.x * 64 + wave * 16;
    int col  = lane & 15, kg = lane >> 4;

    // B fragments (loop-invariant): B[k][c], k = ks*32 + kg*8 + j, c = ct*16 + col
    f16x8 bfrag[4][4];
    #pragma unroll
    for (int ks = 0; ks < 4; ++ks)
        #pragma unroll
        for (int ct = 0; ct < 4; ++ct)
            bfrag[ks][ct] = *(const f16x8*)(W1T + (ct * 16 + col) * IN_DIM + ks * 32 + kg * 8);

    // stage this wave's 16 rows of x as f16 into swizzled LDS
    _Float16* myX = sX[wave];
    #pragma unroll
    for (int it = 0; it < 8; ++it) {
        int idx = it * 64 + lane;          // 512 float4-chunks: row = idx>>5, c4 = idx&31
        int r = idx >> 5, c4 = idx & 31;
        int grow = row0 + r;
        float4 v = make_float4(0.f, 0.f, 0.f, 0.f);
        if (grow < n) v = ((const float4*)x)[(size_t)grow * 32 + c4];
        f16x4 h; h.x = (_Float16)v.x; h.y = (_Float16)v.y; h.z = (_Float16)v.z; h.w = (_Float16)v.w;
        int off = (r * 256 + c4 * 8) ^ ((r & 7) << 4);
        *(f16x4*)((char*)myX + off) = h;
    }
    __syncthreads();

    f32x4 acc[4];
    #pragma unroll
    for (int ct = 0; ct < 4; ++ct) acc[ct] = (f32x4){0.f, 0.f, 0.f, 0.f};

    int arow = lane & 15;
    #pragma unroll
    for (int ks = 0; ks < 4; ++ks) {
        int off = (arow * 256 + kg * 16 + ks * 64) ^ ((arow & 7) << 4);
        f16x8 af = *(const f16x8*)((const char*)myX + off);
        #pragma unroll
        for (int ct = 0; ct < 4; ++ct)
            acc[ct] = __builtin_amdgcn_mfma_f32_16x16x32_f16(af, bfrag[ks][ct], acc[ct], 0, 0, 0);
    }

    // C: row = kg*4 + r, col = ct*16 + (lane&15)
    int crow0 = row0 + kg * 4;
    #pragma unroll
    for (int ct = 0; ct < 4; ++ct)
        #pragma unroll
        for (int r = 0; r < 4; ++r) {
            int gr = crow0 + r;
            if (gr < n) h0[(size_t)gr * HID + ct * 16 + col] = (_Float16)acc[ct][r];
        }
}

// ---------------- GEMM2 (MFMA f16): h2 = h1 @ W2, in/out f16 ----------------

__global__ __launch_bounds__(256) void k_gemm2(const _Float16* __restrict__ h1,
                                               const _Float16* __restrict__ W2T,
                                               _Float16* __restrict__ h2, int n) {
    __shared__ _Float16 sX[4][16 * HID];   // 8 KB total
    int tid  = threadIdx.x;
    int wave = tid >> 6, lane = tid & 63;
    int row0 = blockIdx.x * 64 + wave * 16;
    int col  = lane & 15, kg = lane >> 4;

    f16x8 bfrag[2][4];
    #pragma unroll
    for (int ks = 0; ks < 2; ++ks)
        #pragma unroll
        for (int ct = 0; ct < 4; ++ct)
            bfrag[ks][ct] = *(const f16x8*)(W2T + (ct * 16 + col) * HID + ks * 32 + kg * 8);

    _Float16* myX = sX[wave];
    #pragma unroll
    for (int it = 0; it < 4; ++it) {
        int idx = it * 64 + lane;          // 256 chunks of 4 f16: row = idx>>4, c4 = idx&15
        int r = idx >> 4, c4 = idx & 15;
        int grow = row0 + r;
        f16x4 h = (f16x4){0, 0, 0, 0};
        if (grow < n) h = ((const f16x4*)h1)[(size_t)grow * 16 + c4];
        int off = (r * 128 + c4 * 8) ^ ((r & 7) << 4);
        *(f16x4*)((char*)myX + off) = h;
    }
    __syncthreads();

    f32x4 acc[4];
    #pragma unroll
    for (int ct = 0; ct < 4; ++ct) acc[ct] = (f32x4){0.f, 0.f, 0.f, 0.f};

    int arow = lane & 15;
    #pragma unroll
    for (int ks = 0; ks < 2; ++ks) {
        int off = (arow * 128 + kg * 16 + ks * 64) ^ ((arow & 7) << 4);
        f16x8 af = *(const f16x8*)((const char*)myX + off);
        #pragma unroll
        for (int ct = 0; ct < 4; ++ct)
            acc[ct] = __builtin_amdgcn_mfma_f32_16x16x32_f16(af, bfrag[ks][ct], acc[ct], 0, 0, 0);
    }

    int crow0 = row0 + kg * 4;
    #pragma unroll
    for (int ct = 0; ct < 4; ++ct)
        #pragma unroll
        for (int r = 0; r < 4; ++r) {
            int gr = crow0 + r;
            if (gr < n) h2[(size_t)gr * HID + ct * 16 + col] = (_Float16)acc[ct][r];
        }
}

// ---------------- CSR propagate 1: h1 = relu(segsum + b1), f16 out ----------------

__global__ __launch_bounds__(256) void k_prop1(const int* __restrict__ rowEnd,
                                               const int* __restrict__ ssrc,
                                               const float* __restrict__ snorm,
                                               const _Float16* __restrict__ hin,
                                               const float* __restrict__ dinv,
                                               const float* __restrict__ b1,
                                               _Float16* __restrict__ hout, int n) {
    int wid  = (blockIdx.x * blockDim.x + threadIdx.x) >> 6;
    int lane = threadIdx.x & 63;
    if (wid >= n) return;
    int start = wid ? rowEnd[wid - 1] : 0;
    int end   = rowEnd[wid];
    float di  = dinv[wid];
    float acc = (float)hin[(size_t)wid * HID + lane] * di * di;
    int j = start;
    for (; j + 1 < end; j += 2) {
        int   s0 = ssrc[j],  s1 = ssrc[j + 1];
        float n0 = snorm[j], n1 = snorm[j + 1];
        float v0 = (float)hin[(size_t)s0 * HID + lane];
        float v1 = (float)hin[(size_t)s1 * HID + lane];
        acc = fmaf(v0, n0, acc);
        acc = fmaf(v1, n1, acc);
    }
    if (j < end) acc = fmaf((float)hin[(size_t)ssrc[j] * HID + lane], snorm[j], acc);
    hout[(size_t)wid * HID + lane] = (_Float16)fmaxf(acc + b1[lane], 0.0f);
}

// ---------------- CSR propagate 2 + final linear fused ----------------
// out[row] = sum_lane( relu(segsum + b2)[lane] * Wl[lane] ) + bl

__global__ __launch_bounds__(256) void k_prop2_final(const int* __restrict__ rowEnd,
                                                     const int* __restrict__ ssrc,
                                                     const float* __restrict__ snorm,
                                                     const _Float16* __restrict__ hin,
                                                     const float* __restrict__ dinv,
                                                     const float* __restrict__ b2,
                                                     const float* __restrict__ Wl,
                                                     const float* __restrict__ bl,
                                                     float* __restrict__ out, int n) {
    int wid  = (blockIdx.x * blockDim.x + threadIdx.x) >> 6;
    int lane = threadIdx.x & 63;
    if (wid >= n) return;
    int start = wid ? rowEnd[wid - 1] : 0;
    int end   = rowEnd[wid];
    float di  = dinv[wid];
    float acc = (float)hin[(size_t)wid * HID + lane] * di * di;
    int j = start;
    for (; j + 1 < end; j += 2) {
        int   s0 = ssrc[j],  s1 = ssrc[j + 1];
        float n0 = snorm[j], n1 = snorm[j + 1];
        float v0 = (float)hin[(size_t)s0 * HID + lane];
        float v1 = (float)hin[(size_t)s1 * HID + lane];
        acc = fmaf(v0, n0, acc);
        acc = fmaf(v1, n1, acc);
    }
    if (j < end) acc = fmaf((float)hin[(size_t)ssrc[j] * HID + lane], snorm[j], acc);

    float v = fmaxf(acc + b2[lane], 0.0f) * Wl[lane];
    for (int off = 32; off > 0; off >>= 1)
        v += __shfl_down(v, off);
    if (lane == 0) out[wid] = v + bl[0];
}

// ---------------- launch ----------------

extern "C" void kernel_launch(void* const* d_in, const int* in_sizes, int n_in,
                              void* d_out, int out_size, void* d_ws, size_t ws_size,
                              hipStream_t stream) {
    const float* x   = (const float*)d_in[0];
    const int*   ei  = (const int*)d_in[1];
    const float* ew  = (const float*)d_in[2];
    const float* W1  = (const float*)d_in[3];
    const float* b1  = (const float*)d_in[4];
    const float* W2  = (const float*)d_in[5];
    const float* b2  = (const float*)d_in[6];
    const float* Wl  = (const float*)d_in[7];
    const float* bl  = (const float*)d_in[8];

    const int n = in_sizes[0] / IN_DIM;   // 100000
    const int e = in_sizes[2];            // 1000000
    const int* src = ei;
    const int* dst = ei + e;

    float* out = (float*)d_out;
    const int B256 = 256;
    const int nScanBlocks = (n + SCAN_B - 1) / SCAN_B;

    // workspace layout
    char* p = (char*)d_ws;
    float*    dinv    = (float*)p;            p += (size_t)n * 4;
    int*      offsets = (int*)p;              p += (size_t)n * 4;
    int*      bsums   = (int*)p;              p += 512 * 4;
    int*      ssrc    = (int*)p;              p += (size_t)e * 4;
    float*    snorm   = (float*)p;            p += (size_t)e * 4;
    _Float16* W1T     = (_Float16*)p;         p += IN_DIM * HID * 2;
    _Float16* W2T     = (_Float16*)p;         p += HID * HID * 2;
    _Float16* A       = (_Float16*)p;         p += (size_t)n * HID * 2;
    _Float16* B       = (_Float16*)p;         p += (size_t)n * HID * 2;

    // weights prep (independent)
    k_prep_w<<<(IN_DIM * HID + B256 - 1) / B256, B256, 0, stream>>>(W1, W2, W1T, W2T);

    // histogram of dst
    hipMemsetAsync(offsets, 0, (size_t)n * 4, stream);
    k_hist<<<(e + B256 - 1) / B256, B256, 0, stream>>>(dst, offsets, e);

    // degree -> dinv
    k_deg_init <<<(n + B256 - 1) / B256, B256, 0, stream>>>(dinv, n);
    k_deg_accum<<<(e + B256 - 1) / B256, B256, 0, stream>>>(dst, ew, dinv, e);
    k_dinv     <<<(n + B256 - 1) / B256, B256, 0, stream>>>(dinv, n);

    // exclusive scan of counts -> offsets
    k_scan1<<<nScanBlocks, SCAN_B, 0, stream>>>(offsets, bsums, n);
    k_scan2<<<1, 512, 0, stream>>>(bsums, nScanBlocks);
    k_scan3<<<nScanBlocks, SCAN_B, 0, stream>>>(offsets, bsums, n);

    // scatter into dst-sorted arrays (offsets -> row ends)
    k_scatter<<<(e + B256 - 1) / B256, B256, 0, stream>>>(src, dst, ew, dinv,
                                                         offsets, ssrc, snorm, e);

    const int gemmBlocks = (n + 63) / 64;
    const int propBlocks = (n + 3) / 4;

    // layer 1
    k_gemm1<<<gemmBlocks, B256, 0, stream>>>(x, W1T, A, n);
    k_prop1<<<propBlocks, B256, 0, stream>>>(offsets, ssrc, snorm, A, dinv, b1, B, n);

    // layer 2
    k_gemm2<<<gemmBlocks, B256, 0, stream>>>(B, W2T, A, n);

    // propagate 2 + final linear fused
    k_prop2_final<<<propBlocks, B256, 0, stream>>>(offsets, ssrc, snorm, A, dinv,
                                                   b2, Wl, bl, out, n);
}

// Round 4
// 318.946 us; speedup vs baseline: 2.0455x; 1.1081x over previous
//
#include <hip/hip_runtime.h>

#define IN_DIM 128
#define HID    64
#define SCAN_B 256

typedef __attribute__((ext_vector_type(4))) _Float16 f16x4;
typedef __attribute__((ext_vector_type(8))) _Float16 f16x8;
typedef __attribute__((ext_vector_type(4))) float    f32x4;

// ---------------- weight prep: f32 -> f16, transposed ----------------
__global__ void k_prep_w(const float* __restrict__ W1, const float* __restrict__ W2,
                         _Float16* __restrict__ W1T, _Float16* __restrict__ W2T) {
    int i = blockIdx.x * blockDim.x + threadIdx.x;
    if (i < IN_DIM * HID) { int k = i >> 6, c = i & 63; W1T[c * IN_DIM + k] = (_Float16)W1[i]; }
    if (i < HID * HID)    { int k = i >> 6, c = i & 63; W2T[c * HID + k]    = (_Float16)W2[i]; }
}

// ---------------- fused histogram + weighted degree ----------------
__global__ void k_hist_deg(const int* __restrict__ dst, const float* __restrict__ ew,
                           int* __restrict__ counts, float* __restrict__ deg, int e) {
    int i = blockIdx.x * blockDim.x + threadIdx.x;
    if (i < e) {
        int d = dst[i];
        atomicAdd(&counts[d], 1);
        atomicAdd(&deg[d], ew[i]);
    }
}

// ---------------- scans ----------------
__global__ __launch_bounds__(SCAN_B) void k_scan1(int* __restrict__ data,
                                                  int* __restrict__ blockSums, int n) {
    __shared__ int s[SCAN_B];
    int tid = threadIdx.x;
    int gid = blockIdx.x * SCAN_B + tid;
    int v = (gid < n) ? data[gid] : 0;
    s[tid] = v;
    __syncthreads();
    for (int off = 1; off < SCAN_B; off <<= 1) {
        int t = (tid >= off) ? s[tid - off] : 0;
        __syncthreads();
        s[tid] += t;
        __syncthreads();
    }
    if (gid < n) data[gid] = s[tid] - v;
    if (tid == SCAN_B - 1) blockSums[blockIdx.x] = s[tid];
}

__global__ __launch_bounds__(512) void k_scan2(int* __restrict__ blockSums, int nb) {
    __shared__ int s[512];
    int tid = threadIdx.x;
    int v = (tid < nb) ? blockSums[tid] : 0;
    s[tid] = v;
    __syncthreads();
    for (int off = 1; off < 512; off <<= 1) {
        int t = (tid >= off) ? s[tid - off] : 0;
        __syncthreads();
        s[tid] += t;
        __syncthreads();
    }
    if (tid < nb) blockSums[tid] = s[tid] - v;
}

// scan fixup + dinv = rsqrt(deg + 1) fused (self-loop weight 1; deg+1 >= 1 always)
__global__ __launch_bounds__(SCAN_B) void k_scan3_dinv(int* __restrict__ data,
                                                       const int* __restrict__ blockSums,
                                                       float* __restrict__ deg, int n) {
    int gid = blockIdx.x * SCAN_B + threadIdx.x;
    if (gid < n) {
        data[gid] += blockSums[blockIdx.x];
        deg[gid] = rsqrtf(deg[gid] + 1.0f);
    }
}

// ---------------- scatter into dst-sorted order (edge weight only) ----------------
__global__ void k_scatter(const int* __restrict__ src, const int* __restrict__ dst,
                          const float* __restrict__ ew,
                          int* __restrict__ offsets, int* __restrict__ ssrc,
                          float* __restrict__ sew, int e) {
    int i = blockIdx.x * blockDim.x + threadIdx.x;
    if (i >= e) return;
    int d = dst[i];
    int pos = atomicAdd(&offsets[d], 1);
    ssrc[pos] = src[i];
    sew[pos]  = ew[i];
}

// ---------------- GEMM1 (MFMA f16): g1 = (x @ W1) * dinv[row], out f16 ----------------

__global__ __launch_bounds__(256) void k_gemm1(const float* __restrict__ x,
                                               const _Float16* __restrict__ W1T,
                                               const float* __restrict__ dinv,
                                               _Float16* __restrict__ h0, int n) {
    __shared__ _Float16 sX[4][16 * IN_DIM];   // 16 KB total
    int tid  = threadIdx.x;
    int wave = tid >> 6, lane = tid & 63;
    int row0 = blockIdx.x * 64 + wave * 16;
    int col  = lane & 15, kg = lane >> 4;

    f16x8 bfrag[4][4];
    #pragma unroll
    for (int ks = 0; ks < 4; ++ks)
        #pragma unroll
        for (int ct = 0; ct < 4; ++ct)
            bfrag[ks][ct] = *(const f16x8*)(W1T + (ct * 16 + col) * IN_DIM + ks * 32 + kg * 8);

    _Float16* myX = sX[wave];
    #pragma unroll
    for (int it = 0; it < 8; ++it) {
        int idx = it * 64 + lane;
        int r = idx >> 5, c4 = idx & 31;
        int grow = row0 + r;
        float4 v = make_float4(0.f, 0.f, 0.f, 0.f);
        if (grow < n) v = ((const float4*)x)[(size_t)grow * 32 + c4];
        f16x4 h; h.x = (_Float16)v.x; h.y = (_Float16)v.y; h.z = (_Float16)v.z; h.w = (_Float16)v.w;
        int off = (r * 256 + c4 * 8) ^ ((r & 7) << 4);
        *(f16x4*)((char*)myX + off) = h;
    }
    __syncthreads();

    f32x4 acc[4];
    #pragma unroll
    for (int ct = 0; ct < 4; ++ct) acc[ct] = (f32x4){0.f, 0.f, 0.f, 0.f};

    int arow = lane & 15;
    #pragma unroll
    for (int ks = 0; ks < 4; ++ks) {
        int off = (arow * 256 + kg * 16 + ks * 64) ^ ((arow & 7) << 4);
        f16x8 af = *(const f16x8*)((const char*)myX + off);
        #pragma unroll
        for (int ct = 0; ct < 4; ++ct)
            acc[ct] = __builtin_amdgcn_mfma_f32_16x16x32_f16(af, bfrag[ks][ct], acc[ct], 0, 0, 0);
    }

    int crow0 = row0 + kg * 4;
    #pragma unroll
    for (int r = 0; r < 4; ++r) {
        int gr = crow0 + r;
        if (gr < n) {
            float dv = dinv[gr];
            #pragma unroll
            for (int ct = 0; ct < 4; ++ct)
                h0[(size_t)gr * HID + ct * 16 + col] = (_Float16)(acc[ct][r] * dv);
        }
    }
}

// ---------------- GEMM2 (MFMA f16): g2 = (h1 @ W2) * dinv[row], in/out f16 ----------------

__global__ __launch_bounds__(256) void k_gemm2(const _Float16* __restrict__ h1,
                                               const _Float16* __restrict__ W2T,
                                               const float* __restrict__ dinv,
                                               _Float16* __restrict__ h2, int n) {
    __shared__ _Float16 sX[4][16 * HID];   // 8 KB total
    int tid  = threadIdx.x;
    int wave = tid >> 6, lane = tid & 63;
    int row0 = blockIdx.x * 64 + wave * 16;
    int col  = lane & 15, kg = lane >> 4;

    f16x8 bfrag[2][4];
    #pragma unroll
    for (int ks = 0; ks < 2; ++ks)
        #pragma unroll
        for (int ct = 0; ct < 4; ++ct)
            bfrag[ks][ct] = *(const f16x8*)(W2T + (ct * 16 + col) * HID + ks * 32 + kg * 8);

    _Float16* myX = sX[wave];
    #pragma unroll
    for (int it = 0; it < 4; ++it) {
        int idx = it * 64 + lane;
        int r = idx >> 4, c4 = idx & 15;
        int grow = row0 + r;
        f16x4 h = (f16x4){0, 0, 0, 0};
        if (grow < n) h = ((const f16x4*)h1)[(size_t)grow * 16 + c4];
        int off = (r * 128 + c4 * 8) ^ ((r & 7) << 4);
        *(f16x4*)((char*)myX + off) = h;
    }
    __syncthreads();

    f32x4 acc[4];
    #pragma unroll
    for (int ct = 0; ct < 4; ++ct) acc[ct] = (f32x4){0.f, 0.f, 0.f, 0.f};

    int arow = lane & 15;
    #pragma unroll
    for (int ks = 0; ks < 2; ++ks) {
        int off = (arow * 128 + kg * 16 + ks * 64) ^ ((arow & 7) << 4);
        f16x8 af = *(const f16x8*)((const char*)myX + off);
        #pragma unroll
        for (int ct = 0; ct < 4; ++ct)
            acc[ct] = __builtin_amdgcn_mfma_f32_16x16x32_f16(af, bfrag[ks][ct], acc[ct], 0, 0, 0);
    }

    int crow0 = row0 + kg * 4;
    #pragma unroll
    for (int r = 0; r < 4; ++r) {
        int gr = crow0 + r;
        if (gr < n) {
            float dv = dinv[gr];
            #pragma unroll
            for (int ct = 0; ct < 4; ++ct)
                h2[(size_t)gr * HID + ct * 16 + col] = (_Float16)(acc[ct][r] * dv);
        }
    }
}

// ---------------- CSR propagate 1: h1 = relu(di * (g[wid] + sum g[s]*ew) + b1) ----------------
// hin is pre-scaled by dinv (g = h * dinv), so per-edge norm is just ew; di factored out.

__global__ __launch_bounds__(256) void k_prop1(const int* __restrict__ rowEnd,
                                               const int* __restrict__ ssrc,
                                               const float* __restrict__ sew,
                                               const _Float16* __restrict__ hin,
                                               const float* __restrict__ dinv,
                                               const float* __restrict__ b1,
                                               _Float16* __restrict__ hout, int n) {
    int wid  = (blockIdx.x * blockDim.x + threadIdx.x) >> 6;
    int lane = threadIdx.x & 63;
    if (wid >= n) return;
    int start = wid ? rowEnd[wid - 1] : 0;
    int end   = rowEnd[wid];
    float di  = dinv[wid];
    float bb  = b1[lane];
    float acc = (float)hin[(size_t)wid * HID + lane];   // self term (pre-scaled)

    int j = start;
    for (; j + 8 <= end; j += 8) {
        int s[8]; float w[8], v[8];
        #pragma unroll
        for (int k = 0; k < 8; ++k) s[k] = ssrc[j + k];
        #pragma unroll
        for (int k = 0; k < 8; ++k) w[k] = sew[j + k];
        #pragma unroll
        for (int k = 0; k < 8; ++k) v[k] = (float)hin[(size_t)s[k] * HID + lane];
        #pragma unroll
        for (int k = 0; k < 8; ++k) acc = fmaf(v[k], w[k], acc);
    }
    if (j < end) {
        #pragma unroll
        for (int k = 0; k < 8; ++k) {
            int idx = j + k;
            int cl  = idx < end ? idx : j;           // clamp: j < end so always valid
            float wk = idx < end ? sew[cl] : 0.0f;
            int   sk = ssrc[cl];
            acc = fmaf((float)hin[(size_t)sk * HID + lane], wk, acc);
        }
    }
    hout[(size_t)wid * HID + lane] = (_Float16)fmaxf(fmaf(acc, di, bb), 0.0f);
}

// ---------------- CSR propagate 2 + final linear fused ----------------

__global__ __launch_bounds__(256) void k_prop2_final(const int* __restrict__ rowEnd,
                                                     const int* __restrict__ ssrc,
                                                     const float* __restrict__ sew,
                                                     const _Float16* __restrict__ hin,
                                                     const float* __restrict__ dinv,
                                                     const float* __restrict__ b2,
                                                     const float* __restrict__ Wl,
                                                     const float* __restrict__ bl,
                                                     float* __restrict__ out, int n) {
    int wid  = (blockIdx.x * blockDim.x + threadIdx.x) >> 6;
    int lane = threadIdx.x & 63;
    if (wid >= n) return;
    int start = wid ? rowEnd[wid - 1] : 0;
    int end   = rowEnd[wid];
    float di  = dinv[wid];
    float bb  = b2[lane];
    float wl  = Wl[lane];
    float acc = (float)hin[(size_t)wid * HID + lane];

    int j = start;
    for (; j + 8 <= end; j += 8) {
        int s[8]; float w[8], v[8];
        #pragma unroll
        for (int k = 0; k < 8; ++k) s[k] = ssrc[j + k];
        #pragma unroll
        for (int k = 0; k < 8; ++k) w[k] = sew[j + k];
        #pragma unroll
        for (int k = 0; k < 8; ++k) v[k] = (float)hin[(size_t)s[k] * HID + lane];
        #pragma unroll
        for (int k = 0; k < 8; ++k) acc = fmaf(v[k], w[k], acc);
    }
    if (j < end) {
        #pragma unroll
        for (int k = 0; k < 8; ++k) {
            int idx = j + k;
            int cl  = idx < end ? idx : j;
            float wk = idx < end ? sew[cl] : 0.0f;
            int   sk = ssrc[cl];
            acc = fmaf((float)hin[(size_t)sk * HID + lane], wk, acc);
        }
    }

    float v = fmaxf(fmaf(acc, di, bb), 0.0f) * wl;
    for (int off = 32; off > 0; off >>= 1)
        v += __shfl_down(v, off);
    if (lane == 0) out[wid] = v + bl[0];
}

// ---------------- launch ----------------

extern "C" void kernel_launch(void* const* d_in, const int* in_sizes, int n_in,
                              void* d_out, int out_size, void* d_ws, size_t ws_size,
                              hipStream_t stream) {
    const float* x   = (const float*)d_in[0];
    const int*   ei  = (const int*)d_in[1];
    const float* ew  = (const float*)d_in[2];
    const float* W1  = (const float*)d_in[3];
    const float* b1  = (const float*)d_in[4];
    const float* W2  = (const float*)d_in[5];
    const float* b2  = (const float*)d_in[6];
    const float* Wl  = (const float*)d_in[7];
    const float* bl  = (const float*)d_in[8];

    const int n = in_sizes[0] / IN_DIM;   // 100000
    const int e = in_sizes[2];            // 1000000
    const int* src = ei;
    const int* dst = ei + e;

    float* out = (float*)d_out;
    const int B256 = 256;
    const int nScanBlocks = (n + SCAN_B - 1) / SCAN_B;

    // workspace layout
    char* p = (char*)d_ws;
    float*    dinv    = (float*)p;            p += (size_t)n * 4;   // deg then dinv
    int*      offsets = (int*)p;              p += (size_t)n * 4;
    int*      bsums   = (int*)p;              p += 512 * 4;
    int*      ssrc    = (int*)p;              p += (size_t)e * 4;
    float*    sew     = (float*)p;            p += (size_t)e * 4;
    _Float16* W1T     = (_Float16*)p;         p += IN_DIM * HID * 2;
    _Float16* W2T     = (_Float16*)p;         p += HID * HID * 2;
    _Float16* A       = (_Float16*)p;         p += (size_t)n * HID * 2;
    _Float16* B       = (_Float16*)p;         p += (size_t)n * HID * 2;

    k_prep_w<<<(IN_DIM * HID + B256 - 1) / B256, B256, 0, stream>>>(W1, W2, W1T, W2T);

    // counts=0, deg=0 (contiguous: dinv then offsets)
    hipMemsetAsync(dinv, 0, (size_t)n * 4, stream);
    hipMemsetAsync(offsets, 0, (size_t)n * 4, stream);

    k_hist_deg<<<(e + B256 - 1) / B256, B256, 0, stream>>>(dst, ew, offsets, dinv, e);

    k_scan1<<<nScanBlocks, SCAN_B, 0, stream>>>(offsets, bsums, n);
    k_scan2<<<1, 512, 0, stream>>>(bsums, nScanBlocks);
    k_scan3_dinv<<<nScanBlocks, SCAN_B, 0, stream>>>(offsets, bsums, dinv, n);

    k_scatter<<<(e + B256 - 1) / B256, B256, 0, stream>>>(src, dst, ew, offsets, ssrc, sew, e);

    const int gemmBlocks = (n + 63) / 64;
    const int propBlocks = (n + 3) / 4;

    k_gemm1<<<gemmBlocks, B256, 0, stream>>>(x, W1T, dinv, A, n);
    k_prop1<<<propBlocks, B256, 0, stream>>>(offsets, ssrc, sew, A, dinv, b1, B, n);

    k_gemm2<<<gemmBlocks, B256, 0, stream>>>(B, W2T, dinv, A, n);
    k_prop2_final<<<propBlocks, B256, 0, stream>>>(offsets, ssrc, sew, A, dinv,
                                                   b2, Wl, bl, out, n);
}

// Round 5
// 252.959 us; speedup vs baseline: 2.5792x; 1.2609x over previous
//
#include <hip/hip_runtime.h>

#define IN_DIM 128
#define HID    64
#define SCAN_B 256

typedef __attribute__((ext_vector_type(4))) _Float16 f16x4;
typedef __attribute__((ext_vector_type(8))) _Float16 f16x8;
typedef __attribute__((ext_vector_type(4))) float    f32x4;

// ---------------- weight prep: f32 -> f16, transposed ----------------
__global__ void k_prep_w(const float* __restrict__ W1, const float* __restrict__ W2,
                         _Float16* __restrict__ W1T, _Float16* __restrict__ W2T) {
    int i = blockIdx.x * blockDim.x + threadIdx.x;
    if (i < IN_DIM * HID) { int k = i >> 6, c = i & 63; W1T[c * IN_DIM + k] = (_Float16)W1[i]; }
    if (i < HID * HID)    { int k = i >> 6, c = i & 63; W2T[c * HID + k]    = (_Float16)W2[i]; }
}

// ---------------- histogram with rank capture (1 atomic/edge) ----------------
__global__ void k_hist_rank(const int* __restrict__ dst, int* __restrict__ counts,
                            int* __restrict__ rank, int e) {
    int i = blockIdx.x * blockDim.x + threadIdx.x;
    if (i < e) rank[i] = atomicAdd(&counts[dst[i]], 1);
}

// ---------------- scans ----------------
__global__ __launch_bounds__(SCAN_B) void k_scan1(int* __restrict__ data,
                                                  int* __restrict__ blockSums, int n) {
    __shared__ int s[SCAN_B];
    int tid = threadIdx.x;
    int gid = blockIdx.x * SCAN_B + tid;
    int v = (gid < n) ? data[gid] : 0;
    s[tid] = v;
    __syncthreads();
    for (int off = 1; off < SCAN_B; off <<= 1) {
        int t = (tid >= off) ? s[tid - off] : 0;
        __syncthreads();
        s[tid] += t;
        __syncthreads();
    }
    if (gid < n) data[gid] = s[tid] - v;
    if (tid == SCAN_B - 1) blockSums[blockIdx.x] = s[tid];
}

__global__ __launch_bounds__(512) void k_scan2(int* __restrict__ blockSums, int nb) {
    __shared__ int s[512];
    int tid = threadIdx.x;
    int v = (tid < nb) ? blockSums[tid] : 0;
    s[tid] = v;
    __syncthreads();
    for (int off = 1; off < 512; off <<= 1) {
        int t = (tid >= off) ? s[tid - off] : 0;
        __syncthreads();
        s[tid] += t;
        __syncthreads();
    }
    if (tid < nb) blockSums[tid] = s[tid] - v;
}

// scan fixup; also writes the terminator offsets[n] = e
__global__ __launch_bounds__(SCAN_B) void k_scan3(int* __restrict__ data,
                                                  const int* __restrict__ blockSums,
                                                  int n, int e) {
    int gid = blockIdx.x * SCAN_B + threadIdx.x;
    if (gid < n) {
        data[gid] += blockSums[blockIdx.x];
        if (gid == n - 1) data[n] = e;
    }
}

// ---------------- atomic-free scatter: pos = rowStart[dst] + rank ----------------
__global__ void k_scatter(const int* __restrict__ src, const int* __restrict__ dst,
                          const float* __restrict__ ew, const int* __restrict__ rank,
                          const int* __restrict__ rowOff, int* __restrict__ ssrc,
                          float* __restrict__ sew, int e) {
    int i = blockIdx.x * blockDim.x + threadIdx.x;
    if (i >= e) return;
    int pos = rowOff[dst[i]] + rank[i];
    ssrc[pos] = src[i];
    sew[pos]  = ew[i];
}

// ---------------- weighted degree from sorted weights + dinv ----------------
__global__ void k_deg_dinv(const int* __restrict__ rowOff, const float* __restrict__ sew,
                           float* __restrict__ dinv, int n) {
    int v = blockIdx.x * blockDim.x + threadIdx.x;
    if (v >= n) return;
    int s = rowOff[v], t = rowOff[v + 1];
    float a = 1.0f;                         // self-loop weight
    for (int j = s; j < t; ++j) a += sew[j];
    dinv[v] = rsqrtf(a);
}

// ---------------- GEMM1 (MFMA f16): g1 = (x @ W1) * dinv[row], out f16 ----------------

__global__ __launch_bounds__(256) void k_gemm1(const float* __restrict__ x,
                                               const _Float16* __restrict__ W1T,
                                               const float* __restrict__ dinv,
                                               _Float16* __restrict__ h0, int n) {
    __shared__ _Float16 sX[4][16 * IN_DIM];   // 16 KB total
    int tid  = threadIdx.x;
    int wave = tid >> 6, lane = tid & 63;
    int row0 = blockIdx.x * 64 + wave * 16;
    int col  = lane & 15, kg = lane >> 4;

    f16x8 bfrag[4][4];
    #pragma unroll
    for (int ks = 0; ks < 4; ++ks)
        #pragma unroll
        for (int ct = 0; ct < 4; ++ct)
            bfrag[ks][ct] = *(const f16x8*)(W1T + (ct * 16 + col) * IN_DIM + ks * 32 + kg * 8);

    _Float16* myX = sX[wave];
    #pragma unroll
    for (int it = 0; it < 8; ++it) {
        int idx = it * 64 + lane;
        int r = idx >> 5, c4 = idx & 31;
        int grow = row0 + r;
        float4 v = make_float4(0.f, 0.f, 0.f, 0.f);
        if (grow < n) v = ((const float4*)x)[(size_t)grow * 32 + c4];
        f16x4 h; h.x = (_Float16)v.x; h.y = (_Float16)v.y; h.z = (_Float16)v.z; h.w = (_Float16)v.w;
        int off = (r * 256 + c4 * 8) ^ ((r & 7) << 4);
        *(f16x4*)((char*)myX + off) = h;
    }
    __syncthreads();

    f32x4 acc[4];
    #pragma unroll
    for (int ct = 0; ct < 4; ++ct) acc[ct] = (f32x4){0.f, 0.f, 0.f, 0.f};

    int arow = lane & 15;
    #pragma unroll
    for (int ks = 0; ks < 4; ++ks) {
        int off = (arow * 256 + kg * 16 + ks * 64) ^ ((arow & 7) << 4);
        f16x8 af = *(const f16x8*)((const char*)myX + off);
        #pragma unroll
        for (int ct = 0; ct < 4; ++ct)
            acc[ct] = __builtin_amdgcn_mfma_f32_16x16x32_f16(af, bfrag[ks][ct], acc[ct], 0, 0, 0);
    }

    int crow0 = row0 + kg * 4;
    #pragma unroll
    for (int r = 0; r < 4; ++r) {
        int gr = crow0 + r;
        if (gr < n) {
            float dv = dinv[gr];
            #pragma unroll
            for (int ct = 0; ct < 4; ++ct)
                h0[(size_t)gr * HID + ct * 16 + col] = (_Float16)(acc[ct][r] * dv);
        }
    }
}

// ---------------- GEMM2 (MFMA f16): g2 = (h1 @ W2) * dinv[row], in/out f16 ----------------

__global__ __launch_bounds__(256) void k_gemm2(const _Float16* __restrict__ h1,
                                               const _Float16* __restrict__ W2T,
                                               const float* __restrict__ dinv,
                                               _Float16* __restrict__ h2, int n) {
    __shared__ _Float16 sX[4][16 * HID];   // 8 KB total
    int tid  = threadIdx.x;
    int wave = tid >> 6, lane = tid & 63;
    int row0 = blockIdx.x * 64 + wave * 16;
    int col  = lane & 15, kg = lane >> 4;

    f16x8 bfrag[2][4];
    #pragma unroll
    for (int ks = 0; ks < 2; ++ks)
        #pragma unroll
        for (int ct = 0; ct < 4; ++ct)
            bfrag[ks][ct] = *(const f16x8*)(W2T + (ct * 16 + col) * HID + ks * 32 + kg * 8);

    _Float16* myX = sX[wave];
    #pragma unroll
    for (int it = 0; it < 4; ++it) {
        int idx = it * 64 + lane;
        int r = idx >> 4, c4 = idx & 15;
        int grow = row0 + r;
        f16x4 h = (f16x4){0, 0, 0, 0};
        if (grow < n) h = ((const f16x4*)h1)[(size_t)grow * 16 + c4];
        int off = (r * 128 + c4 * 8) ^ ((r & 7) << 4);
        *(f16x4*)((char*)myX + off) = h;
    }
    __syncthreads();

    f32x4 acc[4];
    #pragma unroll
    for (int ct = 0; ct < 4; ++ct) acc[ct] = (f32x4){0.f, 0.f, 0.f, 0.f};

    int arow = lane & 15;
    #pragma unroll
    for (int ks = 0; ks < 2; ++ks) {
        int off = (arow * 128 + kg * 16 + ks * 64) ^ ((arow & 7) << 4);
        f16x8 af = *(const f16x8*)((const char*)myX + off);
        #pragma unroll
        for (int ct = 0; ct < 4; ++ct)
            acc[ct] = __builtin_amdgcn_mfma_f32_16x16x32_f16(af, bfrag[ks][ct], acc[ct], 0, 0, 0);
    }

    int crow0 = row0 + kg * 4;
    #pragma unroll
    for (int r = 0; r < 4; ++r) {
        int gr = crow0 + r;
        if (gr < n) {
            float dv = dinv[gr];
            #pragma unroll
            for (int ct = 0; ct < 4; ++ct)
                h2[(size_t)gr * HID + ct * 16 + col] = (_Float16)(acc[ct][r] * dv);
        }
    }
}

// ---------------- CSR propagate 1: h1 = relu(di * (g[wid] + sum g[s]*ew) + b1) ----------------

__global__ __launch_bounds__(256) void k_prop1(const int* __restrict__ rowOff,
                                               const int* __restrict__ ssrc,
                                               const float* __restrict__ sew,
                                               const _Float16* __restrict__ hin,
                                               const float* __restrict__ dinv,
                                               const float* __restrict__ b1,
                                               _Float16* __restrict__ hout, int n) {
    int wid  = (blockIdx.x * blockDim.x + threadIdx.x) >> 6;
    int lane = threadIdx.x & 63;
    if (wid >= n) return;
    int start = rowOff[wid];
    int end   = rowOff[wid + 1];
    float di  = dinv[wid];
    float bb  = b1[lane];
    float acc = (float)hin[(size_t)wid * HID + lane];   // self term (pre-scaled)

    int j = start;
    for (; j + 8 <= end; j += 8) {
        int s[8]; float w[8], v[8];
        #pragma unroll
        for (int k = 0; k < 8; ++k) s[k] = ssrc[j + k];
        #pragma unroll
        for (int k = 0; k < 8; ++k) w[k] = sew[j + k];
        #pragma unroll
        for (int k = 0; k < 8; ++k) v[k] = (float)hin[(size_t)s[k] * HID + lane];
        #pragma unroll
        for (int k = 0; k < 8; ++k) acc = fmaf(v[k], w[k], acc);
    }
    if (j < end) {
        #pragma unroll
        for (int k = 0; k < 8; ++k) {
            int idx = j + k;
            int cl  = idx < end ? idx : j;
            float wk = idx < end ? sew[cl] : 0.0f;
            int   sk = ssrc[cl];
            acc = fmaf((float)hin[(size_t)sk * HID + lane], wk, acc);
        }
    }
    hout[(size_t)wid * HID + lane] = (_Float16)fmaxf(fmaf(acc, di, bb), 0.0f);
}

// ---------------- CSR propagate 2 + final linear fused ----------------

__global__ __launch_bounds__(256) void k_prop2_final(const int* __restrict__ rowOff,
                                                     const int* __restrict__ ssrc,
                                                     const float* __restrict__ sew,
                                                     const _Float16* __restrict__ hin,
                                                     const float* __restrict__ dinv,
                                                     const float* __restrict__ b2,
                                                     const float* __restrict__ Wl,
                                                     const float* __restrict__ bl,
                                                     float* __restrict__ out, int n) {
    int wid  = (blockIdx.x * blockDim.x + threadIdx.x) >> 6;
    int lane = threadIdx.x & 63;
    if (wid >= n) return;
    int start = rowOff[wid];
    int end   = rowOff[wid + 1];
    float di  = dinv[wid];
    float bb  = b2[lane];
    float wl  = Wl[lane];
    float acc = (float)hin[(size_t)wid * HID + lane];

    int j = start;
    for (; j + 8 <= end; j += 8) {
        int s[8]; float w[8], v[8];
        #pragma unroll
        for (int k = 0; k < 8; ++k) s[k] = ssrc[j + k];
        #pragma unroll
        for (int k = 0; k < 8; ++k) w[k] = sew[j + k];
        #pragma unroll
        for (int k = 0; k < 8; ++k) v[k] = (float)hin[(size_t)s[k] * HID + lane];
        #pragma unroll
        for (int k = 0; k < 8; ++k) acc = fmaf(v[k], w[k], acc);
    }
    if (j < end) {
        #pragma unroll
        for (int k = 0; k < 8; ++k) {
            int idx = j + k;
            int cl  = idx < end ? idx : j;
            float wk = idx < end ? sew[cl] : 0.0f;
            int   sk = ssrc[cl];
            acc = fmaf((float)hin[(size_t)sk * HID + lane], wk, acc);
        }
    }

    float v = fmaxf(fmaf(acc, di, bb), 0.0f) * wl;
    for (int off = 32; off > 0; off >>= 1)
        v += __shfl_down(v, off);
    if (lane == 0) out[wid] = v + bl[0];
}

// ---------------- launch ----------------

extern "C" void kernel_launch(void* const* d_in, const int* in_sizes, int n_in,
                              void* d_out, int out_size, void* d_ws, size_t ws_size,
                              hipStream_t stream) {
    const float* x   = (const float*)d_in[0];
    const int*   ei  = (const int*)d_in[1];
    const float* ew  = (const float*)d_in[2];
    const float* W1  = (const float*)d_in[3];
    const float* b1  = (const float*)d_in[4];
    const float* W2  = (const float*)d_in[5];
    const float* b2  = (const float*)d_in[6];
    const float* Wl  = (const float*)d_in[7];
    const float* bl  = (const float*)d_in[8];

    const int n = in_sizes[0] / IN_DIM;   // 100000
    const int e = in_sizes[2];            // 1000000
    const int* src = ei;
    const int* dst = ei + e;

    float* out = (float*)d_out;
    const int B256 = 256;
    const int nScanBlocks = (n + SCAN_B - 1) / SCAN_B;

    // workspace layout
    char* p = (char*)d_ws;
    float*    dinv    = (float*)p;            p += (size_t)n * 4;
    int*      offsets = (int*)p;              p += ((size_t)n + 1) * 4;   // counts -> row starts; [n] = e
    int*      bsums   = (int*)p;              p += 512 * 4;
    int*      rank    = (int*)p;              p += (size_t)e * 4;
    int*      ssrc    = (int*)p;              p += (size_t)e * 4;
    float*    sew     = (float*)p;            p += (size_t)e * 4;
    _Float16* W1T     = (_Float16*)p;         p += IN_DIM * HID * 2;
    _Float16* W2T     = (_Float16*)p;         p += HID * HID * 2;
    _Float16* A       = (_Float16*)p;         p += (size_t)n * HID * 2;
    _Float16* B       = (_Float16*)p;         p += (size_t)n * HID * 2;

    k_prep_w<<<(IN_DIM * HID + B256 - 1) / B256, B256, 0, stream>>>(W1, W2, W1T, W2T);

    hipMemsetAsync(offsets, 0, ((size_t)n + 1) * 4, stream);

    // 1 atomic per edge: count + rank capture
    k_hist_rank<<<(e + B256 - 1) / B256, B256, 0, stream>>>(dst, offsets, rank, e);

    // exclusive scan of counts -> row starts (+ terminator)
    k_scan1<<<nScanBlocks, SCAN_B, 0, stream>>>(offsets, bsums, n);
    k_scan2<<<1, 512, 0, stream>>>(bsums, nScanBlocks);
    k_scan3<<<nScanBlocks, SCAN_B, 0, stream>>>(offsets, bsums, n, e);

    // atomic-free scatter
    k_scatter<<<(e + B256 - 1) / B256, B256, 0, stream>>>(src, dst, ew, rank,
                                                         offsets, ssrc, sew, e);

    // weighted degree from sorted weights -> dinv
    k_deg_dinv<<<(n + B256 - 1) / B256, B256, 0, stream>>>(offsets, sew, dinv, n);

    const int gemmBlocks = (n + 63) / 64;
    const int propBlocks = (n + 3) / 4;

    k_gemm1<<<gemmBlocks, B256, 0, stream>>>(x, W1T, dinv, A, n);
    k_prop1<<<propBlocks, B256, 0, stream>>>(offsets, ssrc, sew, A, dinv, b1, B, n);

    k_gemm2<<<gemmBlocks, B256, 0, stream>>>(B, W2T, dinv, A, n);
    k_prop2_final<<<propBlocks, B256, 0, stream>>>(offsets, ssrc, sew, A, dinv,
                                                   b2, Wl, bl, out, n);
}

// Round 6
// 193.186 us; speedup vs baseline: 3.3772x; 1.3094x over previous
//
#include <hip/hip_runtime.h>

#define IN_DIM 128
#define HID    64
#define SCAN_B 256

typedef __attribute__((ext_vector_type(4))) _Float16 f16x4;
typedef __attribute__((ext_vector_type(8))) _Float16 f16x8;
typedef __attribute__((ext_vector_type(4))) float    f32x4;

// ---------------- weight prep: f32 -> f16, transposed ----------------
__global__ void k_prep_w(const float* __restrict__ W1, const float* __restrict__ W2,
                         _Float16* __restrict__ W1T, _Float16* __restrict__ W2T) {
    int i = blockIdx.x * blockDim.x + threadIdx.x;
    if (i < IN_DIM * HID) { int k = i >> 6, c = i & 63; W1T[c * IN_DIM + k] = (_Float16)W1[i]; }
    if (i < HID * HID)    { int k = i >> 6, c = i & 63; W2T[c * HID + k]    = (_Float16)W2[i]; }
}

// ---------------- histogram with rank capture (1 atomic/edge) ----------------
__global__ void k_hist_rank(const int* __restrict__ dst, int* __restrict__ counts,
                            int* __restrict__ rank, int e) {
    int i = blockIdx.x * blockDim.x + threadIdx.x;
    if (i < e) rank[i] = atomicAdd(&counts[dst[i]], 1);
}

// ---------------- scans ----------------
__global__ __launch_bounds__(SCAN_B) void k_scan1(int* __restrict__ data,
                                                  int* __restrict__ blockSums, int n) {
    __shared__ int s[SCAN_B];
    int tid = threadIdx.x;
    int gid = blockIdx.x * SCAN_B + tid;
    int v = (gid < n) ? data[gid] : 0;
    s[tid] = v;
    __syncthreads();
    for (int off = 1; off < SCAN_B; off <<= 1) {
        int t = (tid >= off) ? s[tid - off] : 0;
        __syncthreads();
        s[tid] += t;
        __syncthreads();
    }
    if (gid < n) data[gid] = s[tid] - v;
    if (tid == SCAN_B - 1) blockSums[blockIdx.x] = s[tid];
}

__global__ __launch_bounds__(512) void k_scan2(int* __restrict__ blockSums, int nb) {
    __shared__ int s[512];
    int tid = threadIdx.x;
    int v = (tid < nb) ? blockSums[tid] : 0;
    s[tid] = v;
    __syncthreads();
    for (int off = 1; off < 512; off <<= 1) {
        int t = (tid >= off) ? s[tid - off] : 0;
        __syncthreads();
        s[tid] += t;
        __syncthreads();
    }
    if (tid < nb) blockSums[tid] = s[tid] - v;
}

// scan fixup; also writes the terminator offsets[n] = e
__global__ __launch_bounds__(SCAN_B) void k_scan3(int* __restrict__ data,
                                                  const int* __restrict__ blockSums,
                                                  int n, int e) {
    int gid = blockIdx.x * SCAN_B + threadIdx.x;
    if (gid < n) {
        data[gid] += blockSums[blockIdx.x];
        if (gid == n - 1) data[n] = e;
    }
}

// ---------------- atomic-free scatter: pos = rowStart[dst] + rank ----------------
// packs {src, weight-bits} into one int2 -> single 8B scattered store
__global__ void k_scatter(const int* __restrict__ src, const int* __restrict__ dst,
                          const float* __restrict__ ew, const int* __restrict__ rank,
                          const int* __restrict__ rowOff, int2* __restrict__ sedge, int e) {
    int i = blockIdx.x * blockDim.x + threadIdx.x;
    if (i >= e) return;
    int pos = rowOff[dst[i]] + rank[i];
    sedge[pos] = make_int2(src[i], __float_as_int(ew[i]));
}

// ---------------- weighted degree from sorted weights + dinv ----------------
__global__ void k_deg_dinv(const int* __restrict__ rowOff, const int2* __restrict__ sedge,
                           float* __restrict__ dinv, int n) {
    int v = blockIdx.x * blockDim.x + threadIdx.x;
    if (v >= n) return;
    int s = rowOff[v], t = rowOff[v + 1];
    float a = 1.0f;                         // self-loop weight
    for (int j = s; j < t; ++j) a += __int_as_float(sedge[j].y);
    dinv[v] = rsqrtf(a);
}

// ---------------- GEMM1 (MFMA f16): g1 = (x @ W1) * dinv[row], out f16 ----------------

__global__ __launch_bounds__(256) void k_gemm1(const float* __restrict__ x,
                                               const _Float16* __restrict__ W1T,
                                               const float* __restrict__ dinv,
                                               _Float16* __restrict__ h0, int n) {
    __shared__ _Float16 sX[4][16 * IN_DIM];   // 16 KB total
    int tid  = threadIdx.x;
    int wave = tid >> 6, lane = tid & 63;
    int row0 = blockIdx.x * 64 + wave * 16;
    int col  = lane & 15, kg = lane >> 4;

    f16x8 bfrag[4][4];
    #pragma unroll
    for (int ks = 0; ks < 4; ++ks)
        #pragma unroll
        for (int ct = 0; ct < 4; ++ct)
            bfrag[ks][ct] = *(const f16x8*)(W1T + (ct * 16 + col) * IN_DIM + ks * 32 + kg * 8);

    _Float16* myX = sX[wave];
    #pragma unroll
    for (int it = 0; it < 8; ++it) {
        int idx = it * 64 + lane;
        int r = idx >> 5, c4 = idx & 31;
        int grow = row0 + r;
        float4 v = make_float4(0.f, 0.f, 0.f, 0.f);
        if (grow < n) v = ((const float4*)x)[(size_t)grow * 32 + c4];
        f16x4 h; h.x = (_Float16)v.x; h.y = (_Float16)v.y; h.z = (_Float16)v.z; h.w = (_Float16)v.w;
        int off = (r * 256 + c4 * 8) ^ ((r & 7) << 4);
        *(f16x4*)((char*)myX + off) = h;
    }
    __syncthreads();

    f32x4 acc[4];
    #pragma unroll
    for (int ct = 0; ct < 4; ++ct) acc[ct] = (f32x4){0.f, 0.f, 0.f, 0.f};

    int arow = lane & 15;
    #pragma unroll
    for (int ks = 0; ks < 4; ++ks) {
        int off = (arow * 256 + kg * 16 + ks * 64) ^ ((arow & 7) << 4);
        f16x8 af = *(const f16x8*)((const char*)myX + off);
        #pragma unroll
        for (int ct = 0; ct < 4; ++ct)
            acc[ct] = __builtin_amdgcn_mfma_f32_16x16x32_f16(af, bfrag[ks][ct], acc[ct], 0, 0, 0);
    }

    int crow0 = row0 + kg * 4;
    #pragma unroll
    for (int r = 0; r < 4; ++r) {
        int gr = crow0 + r;
        if (gr < n) {
            float dv = dinv[gr];
            #pragma unroll
            for (int ct = 0; ct < 4; ++ct)
                h0[(size_t)gr * HID + ct * 16 + col] = (_Float16)(acc[ct][r] * dv);
        }
    }
}

// ---------------- GEMM2 (MFMA f16): g2 = (h1 @ W2) * dinv[row], in/out f16 ----------------

__global__ __launch_bounds__(256) void k_gemm2(const _Float16* __restrict__ h1,
                                               const _Float16* __restrict__ W2T,
                                               const float* __restrict__ dinv,
                                               _Float16* __restrict__ h2, int n) {
    __shared__ _Float16 sX[4][16 * HID];   // 8 KB total
    int tid  = threadIdx.x;
    int wave = tid >> 6, lane = tid & 63;
    int row0 = blockIdx.x * 64 + wave * 16;
    int col  = lane & 15, kg = lane >> 4;

    f16x8 bfrag[2][4];
    #pragma unroll
    for (int ks = 0; ks < 2; ++ks)
        #pragma unroll
        for (int ct = 0; ct < 4; ++ct)
            bfrag[ks][ct] = *(const f16x8*)(W2T + (ct * 16 + col) * HID + ks * 32 + kg * 8);

    _Float16* myX = sX[wave];
    #pragma unroll
    for (int it = 0; it < 4; ++it) {
        int idx = it * 64 + lane;
        int r = idx >> 4, c4 = idx & 15;
        int grow = row0 + r;
        f16x4 h = (f16x4){0, 0, 0, 0};
        if (grow < n) h = ((const f16x4*)h1)[(size_t)grow * 16 + c4];
        int off = (r * 128 + c4 * 8) ^ ((r & 7) << 4);
        *(f16x4*)((char*)myX + off) = h;
    }
    __syncthreads();

    f32x4 acc[4];
    #pragma unroll
    for (int ct = 0; ct < 4; ++ct) acc[ct] = (f32x4){0.f, 0.f, 0.f, 0.f};

    int arow = lane & 15;
    #pragma unroll
    for (int ks = 0; ks < 2; ++ks) {
        int off = (arow * 128 + kg * 16 + ks * 64) ^ ((arow & 7) << 4);
        f16x8 af = *(const f16x8*)((const char*)myX + off);
        #pragma unroll
        for (int ct = 0; ct < 4; ++ct)
            acc[ct] = __builtin_amdgcn_mfma_f32_16x16x32_f16(af, bfrag[ks][ct], acc[ct], 0, 0, 0);
    }

    int crow0 = row0 + kg * 4;
    #pragma unroll
    for (int r = 0; r < 4; ++r) {
        int gr = crow0 + r;
        if (gr < n) {
            float dv = dinv[gr];
            #pragma unroll
            for (int ct = 0; ct < 4; ++ct)
                h2[(size_t)gr * HID + ct * 16 + col] = (_Float16)(acc[ct][r] * dv);
        }
    }
}

// ---------------- CSR propagate, 4 nodes per wave ----------------
// lane layout: group g = lane>>4 (node wid4+g), gl = lane&15 (features gl*4..gl*4+3)
// one VMEM gather instruction covers 4 edges (one per group), 512B.

__global__ __launch_bounds__(256) void k_prop1(const int* __restrict__ rowOff,
                                               const int2* __restrict__ sedge,
                                               const _Float16* __restrict__ hin,
                                               const float* __restrict__ dinv,
                                               const float* __restrict__ b1,
                                               _Float16* __restrict__ hout, int n) {
    int wave = (blockIdx.x * blockDim.x + threadIdx.x) >> 6;
    int lane = threadIdx.x & 63;
    int g    = lane >> 4;
    int gl   = lane & 15;
    int node = wave * 4 + g;
    bool valid = node < n;
    int nd = valid ? node : 0;

    int start = rowOff[nd];
    int end   = valid ? rowOff[nd + 1] : start;
    float di  = dinv[nd];
    float4 bb = ((const float4*)b1)[gl];

    const _Float16* rowp = hin + (size_t)nd * HID + gl * 4;
    f16x4 sv = *(const f16x4*)rowp;
    float a0 = (float)sv.x, a1 = (float)sv.y, a2 = (float)sv.z, a3 = (float)sv.w;

    int j = start;
    for (; j + 4 <= end; j += 4) {
        int2 e0 = sedge[j], e1 = sedge[j + 1], e2 = sedge[j + 2], e3 = sedge[j + 3];
        f16x4 v0 = *(const f16x4*)(hin + (size_t)e0.x * HID + gl * 4);
        f16x4 v1 = *(const f16x4*)(hin + (size_t)e1.x * HID + gl * 4);
        f16x4 v2 = *(const f16x4*)(hin + (size_t)e2.x * HID + gl * 4);
        f16x4 v3 = *(const f16x4*)(hin + (size_t)e3.x * HID + gl * 4);
        float w0 = __int_as_float(e0.y), w1 = __int_as_float(e1.y);
        float w2 = __int_as_float(e2.y), w3 = __int_as_float(e3.y);
        a0 = fmaf((float)v0.x, w0, a0); a1 = fmaf((float)v0.y, w0, a1);
        a2 = fmaf((float)v0.z, w0, a2); a3 = fmaf((float)v0.w, w0, a3);
        a0 = fmaf((float)v1.x, w1, a0); a1 = fmaf((float)v1.y, w1, a1);
        a2 = fmaf((float)v1.z, w1, a2); a3 = fmaf((float)v1.w, w1, a3);
        a0 = fmaf((float)v2.x, w2, a0); a1 = fmaf((float)v2.y, w2, a1);
        a2 = fmaf((float)v2.z, w2, a2); a3 = fmaf((float)v2.w, w2, a3);
        a0 = fmaf((float)v3.x, w3, a0); a1 = fmaf((float)v3.y, w3, a1);
        a2 = fmaf((float)v3.z, w3, a2); a3 = fmaf((float)v3.w, w3, a3);
    }
    if (j < end) {
        #pragma unroll
        for (int k = 0; k < 4; ++k) {
            int idx = j + k;
            int cl  = idx < end ? idx : j;
            int2 ed = sedge[cl];
            float w = idx < end ? __int_as_float(ed.y) : 0.0f;
            f16x4 v = *(const f16x4*)(hin + (size_t)ed.x * HID + gl * 4);
            a0 = fmaf((float)v.x, w, a0); a1 = fmaf((float)v.y, w, a1);
            a2 = fmaf((float)v.z, w, a2); a3 = fmaf((float)v.w, w, a3);
        }
    }

    if (valid) {
        f16x4 o;
        o.x = (_Float16)fmaxf(fmaf(a0, di, bb.x), 0.0f);
        o.y = (_Float16)fmaxf(fmaf(a1, di, bb.y), 0.0f);
        o.z = (_Float16)fmaxf(fmaf(a2, di, bb.z), 0.0f);
        o.w = (_Float16)fmaxf(fmaf(a3, di, bb.w), 0.0f);
        *(f16x4*)(hout + (size_t)node * HID + gl * 4) = o;
    }
}

__global__ __launch_bounds__(256) void k_prop2_final(const int* __restrict__ rowOff,
                                                     const int2* __restrict__ sedge,
                                                     const _Float16* __restrict__ hin,
                                                     const float* __restrict__ dinv,
                                                     const float* __restrict__ b2,
                                                     const float* __restrict__ Wl,
                                                     const float* __restrict__ bl,
                                                     float* __restrict__ out, int n) {
    int wave = (blockIdx.x * blockDim.x + threadIdx.x) >> 6;
    int lane = threadIdx.x & 63;
    int g    = lane >> 4;
    int gl   = lane & 15;
    int node = wave * 4 + g;
    bool valid = node < n;
    int nd = valid ? node : 0;

    int start = rowOff[nd];
    int end   = valid ? rowOff[nd + 1] : start;
    float di  = dinv[nd];
    float4 bb = ((const float4*)b2)[gl];
    float4 wl = ((const float4*)Wl)[gl];

    const _Float16* rowp = hin + (size_t)nd * HID + gl * 4;
    f16x4 sv = *(const f16x4*)rowp;
    float a0 = (float)sv.x, a1 = (float)sv.y, a2 = (float)sv.z, a3 = (float)sv.w;

    int j = start;
    for (; j + 4 <= end; j += 4) {
        int2 e0 = sedge[j], e1 = sedge[j + 1], e2 = sedge[j + 2], e3 = sedge[j + 3];
        f16x4 v0 = *(const f16x4*)(hin + (size_t)e0.x * HID + gl * 4);
        f16x4 v1 = *(const f16x4*)(hin + (size_t)e1.x * HID + gl * 4);
        f16x4 v2 = *(const f16x4*)(hin + (size_t)e2.x * HID + gl * 4);
        f16x4 v3 = *(const f16x4*)(hin + (size_t)e3.x * HID + gl * 4);
        float w0 = __int_as_float(e0.y), w1 = __int_as_float(e1.y);
        float w2 = __int_as_float(e2.y), w3 = __int_as_float(e3.y);
        a0 = fmaf((float)v0.x, w0, a0); a1 = fmaf((float)v0.y, w0, a1);
        a2 = fmaf((float)v0.z, w0, a2); a3 = fmaf((float)v0.w, w0, a3);
        a0 = fmaf((float)v1.x, w1, a0); a1 = fmaf((float)v1.y, w1, a1);
        a2 = fmaf((float)v1.z, w1, a2); a3 = fmaf((float)v1.w, w1, a3);
        a0 = fmaf((float)v2.x, w2, a0); a1 = fmaf((float)v2.y, w2, a1);
        a2 = fmaf((float)v2.z, w2, a2); a3 = fmaf((float)v2.w, w2, a3);
        a0 = fmaf((float)v3.x, w3, a0); a1 = fmaf((float)v3.y, w3, a1);
        a2 = fmaf((float)v3.z, w3, a2); a3 = fmaf((float)v3.w, w3, a3);
    }
    if (j < end) {
        #pragma unroll
        for (int k = 0; k < 4; ++k) {
            int idx = j + k;
            int cl  = idx < end ? idx : j;
            int2 ed = sedge[cl];
            float w = idx < end ? __int_as_float(ed.y) : 0.0f;
            f16x4 v = *(const f16x4*)(hin + (size_t)ed.x * HID + gl * 4);
            a0 = fmaf((float)v.x, w, a0); a1 = fmaf((float)v.y, w, a1);
            a2 = fmaf((float)v.z, w, a2); a3 = fmaf((float)v.w, w, a3);
        }
    }

    float r0 = fmaxf(fmaf(a0, di, bb.x), 0.0f);
    float r1 = fmaxf(fmaf(a1, di, bb.y), 0.0f);
    float r2 = fmaxf(fmaf(a2, di, bb.z), 0.0f);
    float r3 = fmaxf(fmaf(a3, di, bb.w), 0.0f);
    float v = r0 * wl.x + r1 * wl.y + r2 * wl.z + r3 * wl.w;
    #pragma unroll
    for (int off = 1; off < 16; off <<= 1)
        v += __shfl_xor(v, off);
    if (valid && gl == 0) out[node] = v + bl[0];
}

// ---------------- launch ----------------

static inline char* align16(char* p) {
    return (char*)(((uintptr_t)p + 15) & ~(uintptr_t)15);
}

extern "C" void kernel_launch(void* const* d_in, const int* in_sizes, int n_in,
                              void* d_out, int out_size, void* d_ws, size_t ws_size,
                              hipStream_t stream) {
    const float* x   = (const float*)d_in[0];
    const int*   ei  = (const int*)d_in[1];
    const float* ew  = (const float*)d_in[2];
    const float* W1  = (const float*)d_in[3];
    const float* b1  = (const float*)d_in[4];
    const float* W2  = (const float*)d_in[5];
    const float* b2  = (const float*)d_in[6];
    const float* Wl  = (const float*)d_in[7];
    const float* bl  = (const float*)d_in[8];

    const int n = in_sizes[0] / IN_DIM;   // 100000
    const int e = in_sizes[2];            // 1000000
    const int* src = ei;
    const int* dst = ei + e;

    float* out = (float*)d_out;
    const int B256 = 256;
    const int nScanBlocks = (n + SCAN_B - 1) / SCAN_B;

    // workspace layout (16B-aligned slices)
    char* p = (char*)d_ws;
    int2*     sedge   = (int2*)p;             p += (size_t)e * 8;
    float*    dinv    = (float*)p;            p += (size_t)n * 4;
    int*      offsets = (int*)p;              p += ((size_t)n + 1) * 4;
    p = align16(p);
    int*      bsums   = (int*)p;              p += 512 * 4;
    int*      rank    = (int*)p;              p += (size_t)e * 4;
    _Float16* W1T     = (_Float16*)p;         p += IN_DIM * HID * 2;
    _Float16* W2T     = (_Float16*)p;         p += HID * HID * 2;
    p = align16(p);
    _Float16* A       = (_Float16*)p;         p += (size_t)n * HID * 2;
    _Float16* B       = (_Float16*)p;         p += (size_t)n * HID * 2;

    k_prep_w<<<(IN_DIM * HID + B256 - 1) / B256, B256, 0, stream>>>(W1, W2, W1T, W2T);

    hipMemsetAsync(offsets, 0, ((size_t)n + 1) * 4, stream);

    // 1 atomic per edge: count + rank capture
    k_hist_rank<<<(e + B256 - 1) / B256, B256, 0, stream>>>(dst, offsets, rank, e);

    // exclusive scan of counts -> row starts (+ terminator)
    k_scan1<<<nScanBlocks, SCAN_B, 0, stream>>>(offsets, bsums, n);
    k_scan2<<<1, 512, 0, stream>>>(bsums, nScanBlocks);
    k_scan3<<<nScanBlocks, SCAN_B, 0, stream>>>(offsets, bsums, n, e);

    // atomic-free scatter (packed edges)
    k_scatter<<<(e + B256 - 1) / B256, B256, 0, stream>>>(src, dst, ew, rank,
                                                         offsets, sedge, e);

    // weighted degree from sorted weights -> dinv
    k_deg_dinv<<<(n + B256 - 1) / B256, B256, 0, stream>>>(offsets, sedge, dinv, n);

    const int gemmBlocks = (n + 63) / 64;
    const int propBlocks = (n + 15) / 16;   // 16 nodes per 256-thread block

    k_gemm1<<<gemmBlocks, B256, 0, stream>>>(x, W1T, dinv, A, n);
    k_prop1<<<propBlocks, B256, 0, stream>>>(offsets, sedge, A, dinv, b1, B, n);

    k_gemm2<<<gemmBlocks, B256, 0, stream>>>(B, W2T, dinv, A, n);
    k_prop2_final<<<propBlocks, B256, 0, stream>>>(offsets, sedge, A, dinv,
                                                   b2, Wl, bl, out, n);
}